// Round 2
// baseline (4945.024 us; speedup 1.0000x reference)
//
#include <hip/hip_runtime.h>
#include <hip/hip_cooperative_groups.h>
#include <cmath>

namespace cg = cooperative_groups;

#define T_  128
#define B_  128
#define I_  256
#define H_  256
#define G4_ 1024

// ================= Phase 1: Gx[t] = x[t] @ Wi[t] + bi[t] + bh[t] =================
// grid 4096 = T(128) * rt(4) * cn(8); block 256. Tile 32 rows x 128 cols, K staged
// in 8 chunks of 32. bid%8 == cn so the 4 rt-blocks sharing a Wi slice share an XCD L2.
__global__ __launch_bounds__(256)
void lstm_phase1(const float* __restrict__ x, const float* __restrict__ Wi,
                 const float* __restrict__ bi, const float* __restrict__ bh,
                 float* __restrict__ Gx)
{
    __shared__ float xs[32][36];     // [row][k] — stride 36 keeps float4 writes 16B-aligned
    __shared__ float ws1[32][128];   // [k][col]

    const int tid = threadIdx.x;
    const int bid = blockIdx.x;
    const int t  = bid >> 5;
    const int rt = (bid >> 3) & 3;
    const int cn = bid & 7;
    const int r0 = rt * 32;
    const int c0 = cn * 128;

    const int tr  = tid >> 5;    // 0..7 -> rows tr*4..+4
    const int tc4 = tid & 31;    // cols tc4*4..+4

    const int xrow = tid >> 3;          // 0..31
    const int xk0  = (tid & 7) * 4;     // 0..28

    float acc[4][4] = {};

    for (int kc = 0; kc < I_; kc += 32) {
        __syncthreads();
        // stage x chunk [32 rows][32 k]
        *(float4*)&xs[xrow][xk0] =
            *(const float4*)&x[(t * B_ + r0 + xrow) * I_ + kc + xk0];
        // stage Wi chunk [32 k][128 cols]
        #pragma unroll
        for (int q = 0; q < 4; ++q) {
            int s  = q * 256 + tid;       // 0..1023
            int k  = s >> 5;
            int c4 = (s & 31) * 4;
            *(float4*)&ws1[k][c4] =
                *(const float4*)&Wi[(t * I_ + kc + k) * G4_ + c0 + c4];
        }
        __syncthreads();
        #pragma unroll
        for (int k = 0; k < 32; ++k) {
            float a0 = xs[tr * 4 + 0][k];
            float a1 = xs[tr * 4 + 1][k];
            float a2 = xs[tr * 4 + 2][k];
            float a3 = xs[tr * 4 + 3][k];
            float4 w4 = *(const float4*)&ws1[k][tc4 * 4];
            acc[0][0] += a0 * w4.x; acc[0][1] += a0 * w4.y; acc[0][2] += a0 * w4.z; acc[0][3] += a0 * w4.w;
            acc[1][0] += a1 * w4.x; acc[1][1] += a1 * w4.y; acc[1][2] += a1 * w4.z; acc[1][3] += a1 * w4.w;
            acc[2][0] += a2 * w4.x; acc[2][1] += a2 * w4.y; acc[2][2] += a2 * w4.z; acc[2][3] += a2 * w4.w;
            acc[3][0] += a3 * w4.x; acc[3][1] += a3 * w4.y; acc[3][2] += a3 * w4.z; acc[3][3] += a3 * w4.w;
        }
    }

    const int col = c0 + tc4 * 4;
    float4 b1 = *(const float4*)&bi[t * G4_ + col];
    float4 b2 = *(const float4*)&bh[t * G4_ + col];
    float bsx = b1.x + b2.x, bsy = b1.y + b2.y, bsz = b1.z + b2.z, bsw = b1.w + b2.w;
    #pragma unroll
    for (int i = 0; i < 4; ++i) {
        float4 o4 = {acc[i][0] + bsx, acc[i][1] + bsy, acc[i][2] + bsz, acc[i][3] + bsw};
        *(float4*)&Gx[(t * B_ + r0 + tr * 4 + i) * G4_ + col] = o4;
    }
}

// ================= Phase 2: recurrence h_t = LSTM(h_{t-1}; Wh[t], Gx[t]) =================
// Cooperative, 256 blocks x 256 thr, 1 grid.sync per step.
// Block (rt=bid>>4, ct=bid&15): rows rt*8..+8, h-cols ct*16..+16 (64 gate cols).
// bid%8 == ct%8 -> 16 blocks sharing a Wh slice share one XCD L2.
// Thread (rh=tid>>7, kq=(tid>>4)&7, jc=tid&15): rows rh*4..+4, col jc (all 4 gates),
// K-range kq*16..+16 per half-pass; partials reduced via LDS.
// Wh(t+1) prefetched into 64 VGPRs during step t (issue-early / commit-late).
__global__ __launch_bounds__(256, 1)
void lstm_phase2(const float* __restrict__ h0, const float* __restrict__ c0in,
                 const float* __restrict__ Wh, const float* __restrict__ Gx,
                 float* __restrict__ out)
{
    cg::grid_group grid = cg::this_grid();

    __shared__ float ws[128 * 64];       // [klocal][j], j swizzled by (klocal>>4)*4 — 32KB
    __shared__ float hs[8][260];         // h_{t-1} rows — 8.3KB
    __shared__ float part[8][8][64];     // [kq][row][j=g*16+jc] — 16KB

    const int tid = threadIdx.x;
    const int rt  = blockIdx.x >> 4;
    const int ct  = blockIdx.x & 15;
    const int r0  = rt * 8;
    const int hc0 = ct * 16;

    const int rh = tid >> 7;           // 0..1
    const int kq = (tid >> 4) & 7;     // 0..7
    const int jc = tid & 15;           // 0..15

    // W global-load mapping: thread holds wreg[q] = Wh[k=q*16+kofs][4 cols]
    const int kofs = tid >> 4;                  // 0..15
    const int j4x  = tid & 15;                  // float4 index within 64-col slice
    const int wcol = (j4x >> 2) * 256 + hc0 + (j4x & 3) * 4;   // global col base

    // swizzled LDS j-indices for compute reads (shift = kq*4, matches write shift q*4)
    int jsw[4];
    #pragma unroll
    for (int g = 0; g < 4; ++g) jsw[g] = (g * 16 + jc + kq * 4) & 63;

    // owner (tid<128) holds one (row, jc) cell's c-state
    const int orow = tid >> 4;    // 0..7 (valid for tid<128)
    const int ojc  = tid & 15;
    float cst = 0.f;
    if (tid < 128) cst = c0in[(r0 + orow) * H_ + hc0 + ojc];

    // prologue: load Wh(t=0) into registers
    float4 wreg[16];
    #pragma unroll
    for (int q = 0; q < 16; ++q)
        wreg[q] = *(const float4*)&Wh[(q * 16 + kofs) * G4_ + wcol];

    for (int t = 0; t < T_; ++t) {
        // ---- stage h_{t-1} (8 rows x 256) ----
        #pragma unroll
        for (int q = 0; q < 2; ++q) {
            int li  = q * 256 + tid;
            int row = li >> 6;
            int kk  = (li & 63) * 4;
            const float* src = (t == 0) ? &h0[(r0 + row) * H_ + kk]
                                        : &out[((t - 1) * B_ + r0 + row) * H_ + kk];
            *(float4*)&hs[row][kk] = *(const float4*)src;
        }

        float acc[4][4] = {};   // [rr][gate]

        #pragma unroll
        for (int p = 0; p < 2; ++p) {
            // commit W half-pass to LDS (swizzle col by q*4 to spread banks)
            #pragma unroll
            for (int q = 0; q < 8; ++q) {
                int qq = p * 8 + q;
                int klocal = q * 16 + kofs;                     // 0..127
                int jw = ((j4x + q) & 15) * 4;                  // (j4x*4 + q*4) & 63
                *(float4*)&ws[klocal * 64 + jw] = wreg[qq];
            }
            __syncthreads();
            if (p == 1) {
                // prefetch Wh(t+1): issued before compute, committed next step (T14)
                int tn = (t + 1 < T_) ? t + 1 : t;
                #pragma unroll
                for (int q = 0; q < 16; ++q)
                    wreg[q] = *(const float4*)&Wh[(tn * 256 + q * 16 + kofs) * G4_ + wcol];
            }
            // compute: 16 k per thread this pass
            #pragma unroll
            for (int kk4 = 0; kk4 < 4; ++kk4) {
                int kl = kq * 16 + kk4 * 4;
                float hv[4][4];
                #pragma unroll
                for (int rr = 0; rr < 4; ++rr) {
                    float4 h4 = *(const float4*)&hs[rh * 4 + rr][p * 128 + kl];
                    hv[rr][0] = h4.x; hv[rr][1] = h4.y; hv[rr][2] = h4.z; hv[rr][3] = h4.w;
                }
                #pragma unroll
                for (int i = 0; i < 4; ++i) {
                    float w0 = ws[(kl + i) * 64 + jsw[0]];
                    float w1 = ws[(kl + i) * 64 + jsw[1]];
                    float w2 = ws[(kl + i) * 64 + jsw[2]];
                    float w3 = ws[(kl + i) * 64 + jsw[3]];
                    #pragma unroll
                    for (int rr = 0; rr < 4; ++rr) {
                        acc[rr][0] += hv[rr][i] * w0;
                        acc[rr][1] += hv[rr][i] * w1;
                        acc[rr][2] += hv[rr][i] * w2;
                        acc[rr][3] += hv[rr][i] * w3;
                    }
                }
            }
            if (p == 0) __syncthreads();   // protect ws before pass-1 overwrite
        }

        // ---- partial reduce ----
        #pragma unroll
        for (int rr = 0; rr < 4; ++rr)
            #pragma unroll
            for (int g = 0; g < 4; ++g)
                part[kq][rh * 4 + rr][g * 16 + jc] = acc[rr][g];
        __syncthreads();

        if (tid < 128) {
            float gate[4];
            #pragma unroll
            for (int g = 0; g < 4; ++g) {
                float s = 0.f;
                #pragma unroll
                for (int k2 = 0; k2 < 8; ++k2) s += part[k2][orow][g * 16 + ojc];
                gate[g] = s + Gx[(t * B_ + r0 + orow) * G4_ + g * 256 + hc0 + ojc];
            }
            float fi = 1.f / (1.f + expf(-gate[0]));
            float ff = 1.f / (1.f + expf(-gate[1]));
            float fo = 1.f / (1.f + expf(-gate[2]));
            float gt = tanhf(gate[3]);
            cst = ff * cst + fi * gt;
            float hvv = fo * tanhf(cst);
            out[(t * B_ + r0 + orow) * H_ + hc0 + ojc] = hvv;
            if (t == T_ - 1) {
                out[T_ * B_ * H_ + (r0 + orow) * H_ + hc0 + ojc] = hvv;
                out[T_ * B_ * H_ + B_ * H_ + (r0 + orow) * H_ + hc0 + ojc] = cst;
            }
        }
        grid.sync();
    }
}

extern "C" void kernel_launch(void* const* d_in, const int* in_sizes, int n_in,
                              void* d_out, int out_size, void* d_ws, size_t ws_size,
                              hipStream_t stream) {
    const float* x  = (const float*)d_in[0];
    const float* h0 = (const float*)d_in[1];
    const float* c0 = (const float*)d_in[2];
    const float* Wi = (const float*)d_in[3];
    const float* bi = (const float*)d_in[4];
    const float* Wh = (const float*)d_in[5];
    const float* bh = (const float*)d_in[6];
    float* out = (float*)d_out;
    float* Gx  = (float*)d_ws;    // T*B*4H fp32 = 67.1 MB

    lstm_phase1<<<dim3(4096), dim3(256), 0, stream>>>(x, Wi, bi, bh, Gx);

    void* args[] = {&h0, &c0, &Wh, &Gx, &out};
    hipLaunchCooperativeKernel((void*)lstm_phase2, dim3(256), dim3(256),
                               args, 0, stream);
}

// Round 3
// 1331.633 us; speedup vs baseline: 3.7135x; 3.7135x over previous
//
#include <hip/hip_runtime.h>
#include <hip/hip_bf16.h>
#include <cmath>

#define T_  128
#define B_  128
#define I_  256
#define H_  256
#define G4_ 1024

using frag  = __attribute__((ext_vector_type(8))) short;   // 8 bf16 = 4 VGPR
using f32x4 = __attribute__((ext_vector_type(4))) float;

__device__ __forceinline__ unsigned short bf16u(float f) {
    __hip_bfloat16 b = __float2bfloat16(f);
    return __builtin_bit_cast(unsigned short, b);
}

// ================= Phase 1a: Gx[t] = x[t] @ Wi[t] + bi[t] + bh[t] (fp32) ========
__global__ __launch_bounds__(256)
void lstm_phase1(const float* __restrict__ x, const float* __restrict__ Wi,
                 const float* __restrict__ bi, const float* __restrict__ bh,
                 float* __restrict__ Gx)
{
    __shared__ float xs[32][36];
    __shared__ float ws1[32][128];

    const int tid = threadIdx.x;
    const int bid = blockIdx.x;
    const int t  = bid >> 5;
    const int rt = (bid >> 3) & 3;
    const int cn = bid & 7;
    const int r0 = rt * 32;
    const int c0 = cn * 128;

    const int tr  = tid >> 5;
    const int tc4 = tid & 31;
    const int xrow = tid >> 3;
    const int xk0  = (tid & 7) * 4;

    float acc[4][4] = {};

    for (int kc = 0; kc < I_; kc += 32) {
        __syncthreads();
        *(float4*)&xs[xrow][xk0] =
            *(const float4*)&x[(t * B_ + r0 + xrow) * I_ + kc + xk0];
        #pragma unroll
        for (int q = 0; q < 4; ++q) {
            int s  = q * 256 + tid;
            int k  = s >> 5;
            int c4 = (s & 31) * 4;
            *(float4*)&ws1[k][c4] =
                *(const float4*)&Wi[(t * I_ + kc + k) * G4_ + c0 + c4];
        }
        __syncthreads();
        #pragma unroll
        for (int k = 0; k < 32; ++k) {
            float a0 = xs[tr * 4 + 0][k];
            float a1 = xs[tr * 4 + 1][k];
            float a2 = xs[tr * 4 + 2][k];
            float a3 = xs[tr * 4 + 3][k];
            float4 w4 = *(const float4*)&ws1[k][tc4 * 4];
            acc[0][0] += a0 * w4.x; acc[0][1] += a0 * w4.y; acc[0][2] += a0 * w4.z; acc[0][3] += a0 * w4.w;
            acc[1][0] += a1 * w4.x; acc[1][1] += a1 * w4.y; acc[1][2] += a1 * w4.z; acc[1][3] += a1 * w4.w;
            acc[2][0] += a2 * w4.x; acc[2][1] += a2 * w4.y; acc[2][2] += a2 * w4.z; acc[2][3] += a2 * w4.w;
            acc[3][0] += a3 * w4.x; acc[3][1] += a3 * w4.y; acc[3][2] += a3 * w4.z; acc[3][3] += a3 * w4.w;
        }
    }

    const int col = c0 + tc4 * 4;
    float4 b1 = *(const float4*)&bi[t * G4_ + col];
    float4 b2 = *(const float4*)&bh[t * G4_ + col];
    float bsx = b1.x + b2.x, bsy = b1.y + b2.y, bsz = b1.z + b2.z, bsw = b1.w + b2.w;
    #pragma unroll
    for (int i = 0; i < 4; ++i) {
        float4 o4 = {acc[i][0] + bsx, acc[i][1] + bsy, acc[i][2] + bsz, acc[i][3] + bsw};
        *(float4*)&Gx[(t * B_ + r0 + tr * 4 + i) * G4_ + col] = o4;
    }
}

// ================= Phase 1b: repack Wh fp32 -> bf16 MFMA-B-fragment layout =====
// Fragment fi = (t*8+kb)*64 + nb  (nb = gatecol-block 0..63). Each fragment:
// 64 lanes x 16B; lane holds Wh[kb*32 + (lane>>4)*8 + j][nb*16 + (lane&15)], j=0..7.
// A and B use the SAME slot->k map, so the contraction is layout-permutation-proof.
__global__ __launch_bounds__(256)
void repack_wh(const float* __restrict__ Wh, unsigned short* __restrict__ Whp)
{
    int gid  = blockIdx.x * 256 + threadIdx.x;   // 128*8*64*64 = 4,194,304 tasks
    int lane = gid & 63;
    int nb   = (gid >> 6) & 63;
    int kb   = (gid >> 12) & 7;
    int t    = gid >> 15;
    int k0   = kb * 32 + (lane >> 4) * 8;
    int col  = nb * 16 + (lane & 15);
    const float* src = Wh + (size_t)(t * I_ + k0) * G4_ + col;
    unsigned short v[8];
    #pragma unroll
    for (int j = 0; j < 8; ++j) v[j] = bf16u(src[(size_t)j * G4_]);
    uint4 o;
    o.x = v[0] | ((unsigned)v[1] << 16);
    o.y = v[2] | ((unsigned)v[3] << 16);
    o.z = v[4] | ((unsigned)v[5] << 16);
    o.w = v[6] | ((unsigned)v[7] << 16);
    *(uint4*)(Whp + (size_t)gid * 8) = o;
}

// ================= Phase 2: recurrence, NO grid sync ===========================
// 8 blocks x 512 threads (8 waves). Block owns 16 batch rows — recurrence is
// row-local so blocks are fully independent. Per step each block streams the
// full Wh[t] (512KB bf16) as ready-made B fragments; h lives in LDS as bf16,
// c in registers. Wave w owns h-cols w*32..+32 (all 4 gates: nb = g*16+w*2+cb).
__global__ __launch_bounds__(512, 1)
void lstm_rec(const float* __restrict__ h0, const float* __restrict__ c0in,
              const unsigned short* __restrict__ Whp,
              const float* __restrict__ Gx, float* __restrict__ out)
{
    __shared__ unsigned short h2[16][272];   // bf16 h rows, stride 544B (bank-spread)

    const int tid  = threadIdx.x;
    const int wv   = tid >> 6;
    const int lane = tid & 63;
    const int r0   = blockIdx.x * 16;
    const int lrow = lane & 15;
    const int lhi  = lane >> 4;

    // stage h0 -> h2
    {
        int row = tid >> 5;            // 0..15
        int cc  = (tid & 31) * 8;
        #pragma unroll
        for (int j = 0; j < 8; ++j)
            h2[row][cc + j] = bf16u(h0[(size_t)(r0 + row) * H_ + cc + j]);
    }
    // c state: row = lhi*4+rg, col = wv*32 + cb*16 + lrow
    float cst[2][4];
    #pragma unroll
    for (int cb = 0; cb < 2; ++cb)
        #pragma unroll
        for (int rg = 0; rg < 4; ++rg)
            cst[cb][rg] = c0in[(size_t)(r0 + lhi * 4 + rg) * H_ + wv * 32 + cb * 16 + lrow];
    __syncthreads();

    const unsigned short* wl = Whp + (size_t)lane * 8;

    for (int t = 0; t < T_; ++t) {
        // Gx prefetch (independent of h — issue early, lands under MFMA loop)
        float gx[4][2][4];
        #pragma unroll
        for (int g = 0; g < 4; ++g)
            #pragma unroll
            for (int cb = 0; cb < 2; ++cb)
                #pragma unroll
                for (int rg = 0; rg < 4; ++rg)
                    gx[g][cb][rg] = Gx[(size_t)(t * B_ + r0 + lhi * 4 + rg) * G4_
                                       + g * 256 + wv * 32 + cb * 16 + lrow];

        f32x4 acc[4][2];
        #pragma unroll
        for (int g = 0; g < 4; ++g)
            #pragma unroll
            for (int cb = 0; cb < 2; ++cb)
                acc[g][cb] = (f32x4){0.f, 0.f, 0.f, 0.f};

        // prologue: load kb=0 fragments
        frag br[2][4][2];
        #pragma unroll
        for (int g = 0; g < 4; ++g)
            #pragma unroll
            for (int cb = 0; cb < 2; ++cb)
                br[0][g][cb] = *(const frag*)(wl +
                    ((size_t)(t * 8 + 0) * 64 + g * 16 + wv * 2 + cb) * 512);

        #pragma unroll
        for (int kb = 0; kb < 8; ++kb) {
            if (kb < 7) {   // prefetch next k-block's 8 fragments
                #pragma unroll
                for (int g = 0; g < 4; ++g)
                    #pragma unroll
                    for (int cb = 0; cb < 2; ++cb)
                        br[(kb + 1) & 1][g][cb] = *(const frag*)(wl +
                            ((size_t)(t * 8 + kb + 1) * 64 + g * 16 + wv * 2 + cb) * 512);
            }
            frag a = *(const frag*)&h2[lrow][kb * 32 + lhi * 8];   // ds_read_b128
            #pragma unroll
            for (int g = 0; g < 4; ++g)
                #pragma unroll
                for (int cb = 0; cb < 2; ++cb)
                    acc[g][cb] = __builtin_amdgcn_mfma_f32_16x16x32_bf16(
                        a, br[kb & 1][g][cb], acc[g][cb], 0, 0, 0);
        }
        __syncthreads();   // all waves done reading h2 before overwrite

        // epilogue: C/D layout col=lane&15, row=(lane>>4)*4+reg (verified m89)
        #pragma unroll
        for (int cb = 0; cb < 2; ++cb) {
            const int colb = wv * 32 + cb * 16 + lrow;
            #pragma unroll
            for (int rg = 0; rg < 4; ++rg) {
                const int row = lhi * 4 + rg;
                float gi = acc[0][cb][rg] + gx[0][cb][rg];
                float gf = acc[1][cb][rg] + gx[1][cb][rg];
                float go = acc[2][cb][rg] + gx[2][cb][rg];
                float gg = acc[3][cb][rg] + gx[3][cb][rg];
                float i_ = 1.f / (1.f + __expf(-gi));
                float f_ = 1.f / (1.f + __expf(-gf));
                float o_ = 1.f / (1.f + __expf(-go));
                float e2 = __expf(2.f * gg);
                float gt = 1.f - 2.f / (e2 + 1.f);
                float c  = f_ * cst[cb][rg] + i_ * gt;
                cst[cb][rg] = c;
                float ec = __expf(2.f * c);
                float tc = 1.f - 2.f / (ec + 1.f);
                float h  = o_ * tc;
                out[(size_t)(t * B_ + r0 + row) * H_ + colb] = h;
                h2[row][colb] = bf16u(h);
                if (t == T_ - 1) {
                    out[(size_t)T_ * B_ * H_ + (size_t)(r0 + row) * H_ + colb] = h;
                    out[(size_t)T_ * B_ * H_ + B_ * H_ + (size_t)(r0 + row) * H_ + colb] = c;
                }
            }
        }
        __syncthreads();   // h2 fully updated before next step's A reads
    }
}

extern "C" void kernel_launch(void* const* d_in, const int* in_sizes, int n_in,
                              void* d_out, int out_size, void* d_ws, size_t ws_size,
                              hipStream_t stream) {
    const float* x  = (const float*)d_in[0];
    const float* h0 = (const float*)d_in[1];
    const float* c0 = (const float*)d_in[2];
    const float* Wi = (const float*)d_in[3];
    const float* bi = (const float*)d_in[4];
    const float* Wh = (const float*)d_in[5];
    const float* bh = (const float*)d_in[6];
    float* out = (float*)d_out;

    float*          Gx  = (float*)d_ws;                              // 67.1 MB
    unsigned short* Whp = (unsigned short*)((char*)d_ws + 67108864); // 67.1 MB

    lstm_phase1<<<dim3(4096), dim3(256), 0, stream>>>(x, Wi, bi, bh, Gx);
    repack_wh<<<dim3(16384), dim3(256), 0, stream>>>(Wh, Whp);
    lstm_rec<<<dim3(8), dim3(512), 0, stream>>>(h0, c0, Whp, Gx, out);
}

// Round 4
// 1163.552 us; speedup vs baseline: 4.2499x; 1.1445x over previous
//
#include <hip/hip_runtime.h>
#include <hip/hip_bf16.h>
#include <cmath>

#define T_  128
#define B_  128
#define I_  256
#define H_  256
#define G4_ 1024

using frag  = __attribute__((ext_vector_type(8))) short;   // 8 bf16 = 4 VGPR
using f32x4 = __attribute__((ext_vector_type(4))) float;

__device__ __forceinline__ unsigned short bf16u(float f) {
    __hip_bfloat16 b = __float2bfloat16(f);
    return __builtin_bit_cast(unsigned short, b);
}

// ================= Phase 1a: Gx[t] = x[t] @ Wi[t] + bi[t] + bh[t] (fp32) ========
__global__ __launch_bounds__(256)
void lstm_phase1(const float* __restrict__ x, const float* __restrict__ Wi,
                 const float* __restrict__ bi, const float* __restrict__ bh,
                 float* __restrict__ Gx)
{
    __shared__ float xs[32][36];
    __shared__ float ws1[32][128];

    const int tid = threadIdx.x;
    const int bid = blockIdx.x;
    const int t  = bid >> 5;
    const int rt = (bid >> 3) & 3;
    const int cn = bid & 7;
    const int r0 = rt * 32;
    const int c0 = cn * 128;

    const int tr  = tid >> 5;
    const int tc4 = tid & 31;
    const int xrow = tid >> 3;
    const int xk0  = (tid & 7) * 4;

    float acc[4][4] = {};

    for (int kc = 0; kc < I_; kc += 32) {
        __syncthreads();
        *(float4*)&xs[xrow][xk0] =
            *(const float4*)&x[(t * B_ + r0 + xrow) * I_ + kc + xk0];
        #pragma unroll
        for (int q = 0; q < 4; ++q) {
            int s  = q * 256 + tid;
            int k  = s >> 5;
            int c4 = (s & 31) * 4;
            *(float4*)&ws1[k][c4] =
                *(const float4*)&Wi[(t * I_ + kc + k) * G4_ + c0 + c4];
        }
        __syncthreads();
        #pragma unroll
        for (int k = 0; k < 32; ++k) {
            float a0 = xs[tr * 4 + 0][k];
            float a1 = xs[tr * 4 + 1][k];
            float a2 = xs[tr * 4 + 2][k];
            float a3 = xs[tr * 4 + 3][k];
            float4 w4 = *(const float4*)&ws1[k][tc4 * 4];
            acc[0][0] += a0 * w4.x; acc[0][1] += a0 * w4.y; acc[0][2] += a0 * w4.z; acc[0][3] += a0 * w4.w;
            acc[1][0] += a1 * w4.x; acc[1][1] += a1 * w4.y; acc[1][2] += a1 * w4.z; acc[1][3] += a1 * w4.w;
            acc[2][0] += a2 * w4.x; acc[2][1] += a2 * w4.y; acc[2][2] += a2 * w4.z; acc[2][3] += a2 * w4.w;
            acc[3][0] += a3 * w4.x; acc[3][1] += a3 * w4.y; acc[3][2] += a3 * w4.z; acc[3][3] += a3 * w4.w;
        }
    }

    const int col = c0 + tc4 * 4;
    float4 b1 = *(const float4*)&bi[t * G4_ + col];
    float4 b2 = *(const float4*)&bh[t * G4_ + col];
    float bsx = b1.x + b2.x, bsy = b1.y + b2.y, bsz = b1.z + b2.z, bsw = b1.w + b2.w;
    #pragma unroll
    for (int i = 0; i < 4; ++i) {
        float4 o4 = {acc[i][0] + bsx, acc[i][1] + bsy, acc[i][2] + bsz, acc[i][3] + bsw};
        *(float4*)&Gx[(t * B_ + r0 + tr * 4 + i) * G4_ + col] = o4;
    }
}

// ================= Phase 1b: repack Wh fp32 -> bf16 MFMA-B-fragment layout =====
// Fragment fi = (t*8+kb)*64 + nb (nb = g*16 + colblock). 64 lanes x 16B; lane
// holds Wh[kb*32 + (lane>>4)*8 + j][nb*16 + (lane&15)], j=0..7. A and B use the
// same slot->k map so the contraction is layout-permutation-proof.
__global__ __launch_bounds__(256)
void repack_wh(const float* __restrict__ Wh, unsigned short* __restrict__ Whp)
{
    int gid  = blockIdx.x * 256 + threadIdx.x;   // 4,194,304 tasks
    int lane = gid & 63;
    int nb   = (gid >> 6) & 63;
    int kb   = (gid >> 12) & 7;
    int t    = gid >> 15;
    int k0   = kb * 32 + (lane >> 4) * 8;
    int col  = nb * 16 + (lane & 15);
    const float* src = Wh + (size_t)(t * I_ + k0) * G4_ + col;
    unsigned short v[8];
    #pragma unroll
    for (int j = 0; j < 8; ++j) v[j] = bf16u(src[(size_t)j * G4_]);
    uint4 o;
    o.x = v[0] | ((unsigned)v[1] << 16);
    o.y = v[2] | ((unsigned)v[3] << 16);
    o.z = v[4] | ((unsigned)v[5] << 16);
    o.w = v[6] | ((unsigned)v[7] << 16);
    *(uint4*)(Whp + (size_t)gid * 8) = o;
}

// ================= Phase 2: recurrence, deep-pipelined weight stream ===========
// 8 blocks x 512 threads. Block owns 16 batch rows (row-local recurrence, no
// grid sync). Weight fragments stream through a 4-deep register ring (32 loads
// in flight per wave) crossing step boundaries — only MFMA is gated by h_t.
// Gx is folded into the MFMA C-input. Epilogue uses v_rcp_f32.
__global__ __launch_bounds__(512, 1)
void lstm_rec(const float* __restrict__ h0, const float* __restrict__ c0in,
              const unsigned short* __restrict__ Whp,
              const float* __restrict__ Gx, float* __restrict__ out)
{
    __shared__ unsigned short h2[16][272];   // bf16 h rows, stride 544B

    const int tid  = threadIdx.x;
    const int wv   = tid >> 6;
    const int lane = tid & 63;
    const int r0   = blockIdx.x * 16;
    const int lrow = lane & 15;
    const int lhi  = lane >> 4;

    // stage h0 -> h2
    {
        int row = tid >> 5;
        int cc  = (tid & 31) * 8;
        #pragma unroll
        for (int j = 0; j < 8; ++j)
            h2[row][cc + j] = bf16u(h0[(size_t)(r0 + row) * H_ + cc + j]);
    }
    float cst[2][4];
    #pragma unroll
    for (int cb = 0; cb < 2; ++cb)
        #pragma unroll
        for (int rg = 0; rg < 4; ++rg)
            cst[cb][rg] = c0in[(size_t)(r0 + lhi * 4 + rg) * H_ + wv * 32 + cb * 16 + lrow];
    __syncthreads();

    const unsigned short* wl = Whp + (size_t)lane * 8;

    // 4-deep fragment ring: br[kb&3][g*2+cb]
    frag br[4][8];
    #pragma unroll
    for (int c = 0; c < 4; ++c)
        #pragma unroll
        for (int g = 0; g < 4; ++g)
            #pragma unroll
            for (int cb = 0; cb < 2; ++cb)
                br[c][g * 2 + cb] = *(const frag*)(wl +
                    (size_t)(c * 64 + g * 16 + wv * 2 + cb) * 512);

    for (int t = 0; t < T_; ++t) {
        // acc init = Gx (exact C/D fragment layout: col=lane&15, row=lhi*4+rg)
        f32x4 acc[4][2];
        #pragma unroll
        for (int g = 0; g < 4; ++g)
            #pragma unroll
            for (int cb = 0; cb < 2; ++cb)
                #pragma unroll
                for (int rg = 0; rg < 4; ++rg)
                    acc[g][cb][rg] = Gx[(size_t)(t * B_ + r0 + lhi * 4 + rg) * G4_
                                        + g * 256 + wv * 32 + cb * 16 + lrow];

        #pragma unroll
        for (int kb = 0; kb < 8; ++kb) {
            const int slot = kb & 3;
            frag a = *(const frag*)&h2[lrow][kb * 32 + lhi * 8];
            #pragma unroll
            for (int g = 0; g < 4; ++g)
                #pragma unroll
                for (int cb = 0; cb < 2; ++cb)
                    acc[g][cb] = __builtin_amdgcn_mfma_f32_16x16x32_bf16(
                        a, br[slot][g * 2 + cb], acc[g][cb], 0, 0, 0);
            // prefetch chunk (t,kb)+4 into the just-freed slot
            const int tn = (kb < 4) ? t : t + 1;
            const int kn = (kb < 4) ? kb + 4 : kb - 4;
            if (tn < T_) {
                #pragma unroll
                for (int g = 0; g < 4; ++g)
                    #pragma unroll
                    for (int cb = 0; cb < 2; ++cb)
                        br[slot][g * 2 + cb] = *(const frag*)(wl +
                            (size_t)((tn * 8 + kn) * 64 + g * 16 + wv * 2 + cb) * 512);
            }
        }
        __syncthreads();   // all waves done reading h2

        #pragma unroll
        for (int cb = 0; cb < 2; ++cb) {
            const int colb = wv * 32 + cb * 16 + lrow;
            #pragma unroll
            for (int rg = 0; rg < 4; ++rg) {
                const int row = lhi * 4 + rg;
                float gi = acc[0][cb][rg];
                float gf = acc[1][cb][rg];
                float go = acc[2][cb][rg];
                float gg = acc[3][cb][rg];
                float i_ = __builtin_amdgcn_rcpf(1.f + __expf(-gi));
                float f_ = __builtin_amdgcn_rcpf(1.f + __expf(-gf));
                float o_ = __builtin_amdgcn_rcpf(1.f + __expf(-go));
                float gt = 1.f - 2.f * __builtin_amdgcn_rcpf(__expf(2.f * gg) + 1.f);
                float c  = f_ * cst[cb][rg] + i_ * gt;
                cst[cb][rg] = c;
                float tc = 1.f - 2.f * __builtin_amdgcn_rcpf(__expf(2.f * c) + 1.f);
                float h  = o_ * tc;
                out[(size_t)(t * B_ + r0 + row) * H_ + colb] = h;
                h2[row][colb] = bf16u(h);
                if (t == T_ - 1) {
                    out[(size_t)T_ * B_ * H_ + (size_t)(r0 + row) * H_ + colb] = h;
                    out[(size_t)T_ * B_ * H_ + B_ * H_ + (size_t)(r0 + row) * H_ + colb] = c;
                }
            }
        }
        __syncthreads();   // h2 fully updated before next step's A reads
    }
}

extern "C" void kernel_launch(void* const* d_in, const int* in_sizes, int n_in,
                              void* d_out, int out_size, void* d_ws, size_t ws_size,
                              hipStream_t stream) {
    const float* x  = (const float*)d_in[0];
    const float* h0 = (const float*)d_in[1];
    const float* c0 = (const float*)d_in[2];
    const float* Wi = (const float*)d_in[3];
    const float* bi = (const float*)d_in[4];
    const float* Wh = (const float*)d_in[5];
    const float* bh = (const float*)d_in[6];
    float* out = (float*)d_out;

    float*          Gx  = (float*)d_ws;                              // 67.1 MB
    unsigned short* Whp = (unsigned short*)((char*)d_ws + 67108864); // 67.1 MB

    lstm_phase1<<<dim3(4096), dim3(256), 0, stream>>>(x, Wi, bi, bh, Gx);
    repack_wh<<<dim3(16384), dim3(256), 0, stream>>>(Wh, Whp);
    lstm_rec<<<dim3(8), dim3(512), 0, stream>>>(h0, c0, Whp, Gx, out);
}

// Round 5
// 989.712 us; speedup vs baseline: 4.9964x; 1.1756x over previous
//
#include <hip/hip_runtime.h>
#include <hip/hip_bf16.h>
#include <cmath>

#define T_  128
#define B_  128
#define I_  256
#define H_  256
#define G4_ 1024

using frag  = __attribute__((ext_vector_type(8))) short;   // 8 bf16 = 4 VGPR
using f32x4 = __attribute__((ext_vector_type(4))) float;

__device__ __forceinline__ unsigned short bf16u(float f) {
    __hip_bfloat16 b = __float2bfloat16(f);
    return __builtin_bit_cast(unsigned short, b);
}

// ================= Phase 1a: Gxp[t] = x[t] @ Wi[t] + bi[t] + bh[t] (fp32) ======
// Output written directly in MFMA C/D fragment layout:
// Gxp[(((t*8+rb)*64)+nb)*256 + lane*4 + rg]  where for element (row gr, gatecol gc):
// rb=gr>>4, rloc=gr&15, lane=(gc&15)|((rloc>>2)<<4), rg=rloc&3, nb=gc>>4.
__global__ __launch_bounds__(256)
void lstm_phase1(const float* __restrict__ x, const float* __restrict__ Wi,
                 const float* __restrict__ bi, const float* __restrict__ bh,
                 float* __restrict__ Gxp)
{
    __shared__ float xs[32][36];
    __shared__ float ws1[32][128];

    const int tid = threadIdx.x;
    const int bid = blockIdx.x;
    const int t  = bid >> 5;
    const int rt = (bid >> 3) & 3;
    const int cn = bid & 7;
    const int r0 = rt * 32;
    const int c0 = cn * 128;

    const int tr  = tid >> 5;
    const int tc4 = tid & 31;
    const int xrow = tid >> 3;
    const int xk0  = (tid & 7) * 4;

    float acc[4][4] = {};

    for (int kc = 0; kc < I_; kc += 32) {
        __syncthreads();
        *(float4*)&xs[xrow][xk0] =
            *(const float4*)&x[(t * B_ + r0 + xrow) * I_ + kc + xk0];
        #pragma unroll
        for (int q = 0; q < 4; ++q) {
            int s  = q * 256 + tid;
            int k  = s >> 5;
            int c4 = (s & 31) * 4;
            *(float4*)&ws1[k][c4] =
                *(const float4*)&Wi[(t * I_ + kc + k) * G4_ + c0 + c4];
        }
        __syncthreads();
        #pragma unroll
        for (int k = 0; k < 32; ++k) {
            float a0 = xs[tr * 4 + 0][k];
            float a1 = xs[tr * 4 + 1][k];
            float a2 = xs[tr * 4 + 2][k];
            float a3 = xs[tr * 4 + 3][k];
            float4 w4 = *(const float4*)&ws1[k][tc4 * 4];
            acc[0][0] += a0 * w4.x; acc[0][1] += a0 * w4.y; acc[0][2] += a0 * w4.z; acc[0][3] += a0 * w4.w;
            acc[1][0] += a1 * w4.x; acc[1][1] += a1 * w4.y; acc[1][2] += a1 * w4.z; acc[1][3] += a1 * w4.w;
            acc[2][0] += a2 * w4.x; acc[2][1] += a2 * w4.y; acc[2][2] += a2 * w4.z; acc[2][3] += a2 * w4.w;
            acc[3][0] += a3 * w4.x; acc[3][1] += a3 * w4.y; acc[3][2] += a3 * w4.z; acc[3][3] += a3 * w4.w;
        }
    }

    const int col = c0 + tc4 * 4;
    float4 b1 = *(const float4*)&bi[t * G4_ + col];
    float4 b2 = *(const float4*)&bh[t * G4_ + col];
    float bs[4] = {b1.x + b2.x, b1.y + b2.y, b1.z + b2.z, b1.w + b2.w};
    #pragma unroll
    for (int i = 0; i < 4; ++i) {
        const int gr   = r0 + tr * 4 + i;
        const int rb   = gr >> 4;
        const int rloc = gr & 15;
        #pragma unroll
        for (int j = 0; j < 4; ++j) {
            const int gc   = col + j;
            const int lane = (gc & 15) | ((rloc >> 2) << 4);
            Gxp[(((size_t)t * 8 + rb) * 64 + (gc >> 4)) * 256 + lane * 4 + (rloc & 3)]
                = acc[i][j] + bs[j];
        }
    }
}

// ================= Phase 1b: repack Wh fp32 -> bf16 MFMA-B-fragment layout =====
__global__ __launch_bounds__(256)
void repack_wh(const float* __restrict__ Wh, unsigned short* __restrict__ Whp)
{
    int gid  = blockIdx.x * 256 + threadIdx.x;   // 4,194,304 tasks
    int lane = gid & 63;
    int nb   = (gid >> 6) & 63;
    int kb   = (gid >> 12) & 7;
    int t    = gid >> 15;
    int k0   = kb * 32 + (lane >> 4) * 8;
    int col  = nb * 16 + (lane & 15);
    const float* src = Wh + (size_t)(t * I_ + k0) * G4_ + col;
    unsigned short v[8];
    #pragma unroll
    for (int j = 0; j < 8; ++j) v[j] = bf16u(src[(size_t)j * G4_]);
    uint4 o;
    o.x = v[0] | ((unsigned)v[1] << 16);
    o.y = v[2] | ((unsigned)v[3] << 16);
    o.z = v[4] | ((unsigned)v[5] << 16);
    o.w = v[6] | ((unsigned)v[7] << 16);
    *(uint4*)(Whp + (size_t)gid * 8) = o;
}

// ================= Phase 2: recurrence + per-XCD L2-warming helpers ============
// Blocks 0..7: recurrence (16 batch rows each, no inter-block deps).
// Blocks 8..15: helper prefetchers; bid%8 pairs helper with recurrence block on
// the same XCD (round-robin dispatch heuristic) — they walk Whp 3 steps ahead
// of the paced progress flag so recurrence weight loads hit local L2, not LLC.
// Raw s_barrier (no vmcnt drain) + double-buffered h keeps the 4-deep weight
// ring and next-step Gx loads in flight across the single per-step barrier.
__global__ __launch_bounds__(512, 1)
void lstm_rec(const float* __restrict__ h0, const float* __restrict__ c0in,
              const unsigned short* __restrict__ Whp,
              const float* __restrict__ Gxp, float* __restrict__ out,
              int* flags)
{
    // ---------------- helper role ----------------
    if (blockIdx.x >= 8) {
        if (!flags) return;
        const int b = blockIdx.x - 8;
        int* fl = flags + b * 32;
        int done = 0;
        float sink = 0.f;
        while (true) {
            int p = __hip_atomic_load(fl, __ATOMIC_RELAXED, __HIP_MEMORY_SCOPE_AGENT);
            if (p >= T_) break;
            int tgt = p + 3; if (tgt > T_) tgt = T_;
            if (done < tgt) {
                for (int t2 = done; t2 < tgt; ++t2) {
                    const unsigned short* base = Whp + (size_t)t2 * 262144;
                    for (int i = threadIdx.x; i < 4096; i += 512)
                        sink += (float)base[(size_t)i * 64];   // one touch per 128B line
                }
                done = tgt;
            } else {
                __builtin_amdgcn_s_sleep(2);
            }
        }
        asm volatile("" :: "v"(sink));
        return;
    }

    // ---------------- recurrence role ----------------
    __shared__ unsigned short h2[2][16][272];   // double-buffered bf16 h rows

    const int tid  = threadIdx.x;
    const int wv   = tid >> 6;
    const int lane = tid & 63;
    const int bid  = blockIdx.x;
    const int r0   = bid * 16;
    const int lrow = lane & 15;
    const int lhi  = lane >> 4;

    {   // stage h0 -> h2[0]
        int row = tid >> 5;
        int cc  = (tid & 31) * 8;
        #pragma unroll
        for (int j = 0; j < 8; ++j)
            h2[0][row][cc + j] = bf16u(h0[(size_t)(r0 + row) * H_ + cc + j]);
    }
    float cst[2][4];
    #pragma unroll
    for (int cb = 0; cb < 2; ++cb)
        #pragma unroll
        for (int rg = 0; rg < 4; ++rg)
            cst[cb][rg] = c0in[(size_t)(r0 + lhi * 4 + rg) * H_ + wv * 32 + cb * 16 + lrow];
    __syncthreads();

    const unsigned short* wl = Whp + (size_t)lane * 8;
    const float*          gl = Gxp + (size_t)lane * 4;

    // 4-deep weight fragment ring + 1-step Gx double buffer
    frag  br[4][8];
    f32x4 gxr[8];
    #pragma unroll
    for (int c = 0; c < 4; ++c)
        #pragma unroll
        for (int g = 0; g < 4; ++g)
            #pragma unroll
            for (int cb = 0; cb < 2; ++cb)
                br[c][g * 2 + cb] = *(const frag*)(wl +
                    (size_t)(c * 64 + g * 16 + wv * 2 + cb) * 512);
    #pragma unroll
    for (int g = 0; g < 4; ++g)
        #pragma unroll
        for (int cb = 0; cb < 2; ++cb)
            gxr[g * 2 + cb] = *(const f32x4*)(gl +
                (size_t)((0 * 8 + bid) * 64 + g * 16 + wv * 2 + cb) * 256);

    for (int t = 0; t < T_; ++t) {
        // acc = Gx fragment (C-input), then refill gxr for t+1 (lands during step)
        f32x4 acc[4][2];
        #pragma unroll
        for (int g = 0; g < 4; ++g)
            #pragma unroll
            for (int cb = 0; cb < 2; ++cb)
                acc[g][cb] = gxr[g * 2 + cb];
        if (t + 1 < T_) {
            #pragma unroll
            for (int g = 0; g < 4; ++g)
                #pragma unroll
                for (int cb = 0; cb < 2; ++cb)
                    gxr[g * 2 + cb] = *(const f32x4*)(gl +
                        (size_t)(((t + 1) * 8 + bid) * 64 + g * 16 + wv * 2 + cb) * 256);
        }

        #pragma unroll
        for (int kb = 0; kb < 8; ++kb) {
            const int slot = kb & 3;
            frag a = *(const frag*)&h2[t & 1][lrow][kb * 32 + lhi * 8];
            #pragma unroll
            for (int g = 0; g < 4; ++g)
                #pragma unroll
                for (int cb = 0; cb < 2; ++cb)
                    acc[g][cb] = __builtin_amdgcn_mfma_f32_16x16x32_bf16(
                        a, br[slot][g * 2 + cb], acc[g][cb], 0, 0, 0);
            const int tn = (kb < 4) ? t : t + 1;
            const int kn = (kb < 4) ? kb + 4 : kb - 4;
            if (tn < T_) {
                #pragma unroll
                for (int g = 0; g < 4; ++g)
                    #pragma unroll
                    for (int cb = 0; cb < 2; ++cb)
                        br[slot][g * 2 + cb] = *(const frag*)(wl +
                            (size_t)((tn * 8 + kn) * 64 + g * 16 + wv * 2 + cb) * 512);
            }
        }

        // epilogue -> h2[(t+1)&1] (other buffer: no WAR with this step's readers)
        #pragma unroll
        for (int cb = 0; cb < 2; ++cb) {
            const int colb = wv * 32 + cb * 16 + lrow;
            #pragma unroll
            for (int rg = 0; rg < 4; ++rg) {
                const int row = lhi * 4 + rg;
                float gi = acc[0][cb][rg];
                float gf = acc[1][cb][rg];
                float go = acc[2][cb][rg];
                float gg = acc[3][cb][rg];
                float i_ = __builtin_amdgcn_rcpf(1.f + __expf(-gi));
                float f_ = __builtin_amdgcn_rcpf(1.f + __expf(-gf));
                float o_ = __builtin_amdgcn_rcpf(1.f + __expf(-go));
                float gt = 1.f - 2.f * __builtin_amdgcn_rcpf(__expf(2.f * gg) + 1.f);
                float c  = f_ * cst[cb][rg] + i_ * gt;
                cst[cb][rg] = c;
                float tc = 1.f - 2.f * __builtin_amdgcn_rcpf(__expf(2.f * c) + 1.f);
                float h  = o_ * tc;
                out[(size_t)(t * B_ + r0 + row) * H_ + colb] = h;
                h2[(t + 1) & 1][row][colb] = bf16u(h);
                if (t == T_ - 1) {
                    out[(size_t)T_ * B_ * H_ + (size_t)(r0 + row) * H_ + colb] = h;
                    out[(size_t)T_ * B_ * H_ + B_ * H_ + (size_t)(r0 + row) * H_ + colb] = c;
                }
            }
        }

        if (flags && tid == 0)
            __hip_atomic_store(flags + bid * 32, t + 1,
                               __ATOMIC_RELAXED, __HIP_MEMORY_SCOPE_AGENT);

        // single per-step barrier: LDS writes visible, global prefetches STAY in flight
        __builtin_amdgcn_sched_barrier(0);
        asm volatile("s_waitcnt lgkmcnt(0)" ::: "memory");
        __builtin_amdgcn_s_barrier();
        __builtin_amdgcn_sched_barrier(0);
    }
}

extern "C" void kernel_launch(void* const* d_in, const int* in_sizes, int n_in,
                              void* d_out, int out_size, void* d_ws, size_t ws_size,
                              hipStream_t stream) {
    const float* x  = (const float*)d_in[0];
    const float* h0 = (const float*)d_in[1];
    const float* c0 = (const float*)d_in[2];
    const float* Wi = (const float*)d_in[3];
    const float* bi = (const float*)d_in[4];
    const float* Wh = (const float*)d_in[5];
    const float* bh = (const float*)d_in[6];
    float* out = (float*)d_out;

    float*          Gxp = (float*)d_ws;                              // 64 MiB
    unsigned short* Whp = (unsigned short*)((char*)d_ws + 67108864); // 64 MiB
    int* flags = nullptr;
    if (ws_size >= 134217728 + 1024) {
        flags = (int*)((char*)d_ws + 134217728);
        hipMemsetAsync(flags, 0, 1024, stream);
    }

    lstm_phase1<<<dim3(4096), dim3(256), 0, stream>>>(x, Wi, bi, bh, Gxp);
    repack_wh<<<dim3(16384), dim3(256), 0, stream>>>(Wh, Whp);
    lstm_rec<<<dim3(16), dim3(512), 0, stream>>>(h0, c0, Whp, Gxp, out, flags);
}

// Round 6
// 841.766 us; speedup vs baseline: 5.8746x; 1.1758x over previous
//
#include <hip/hip_runtime.h>
#include <hip/hip_bf16.h>
#include <cmath>

#define T_  128
#define B_  128
#define I_  256
#define H_  256
#define G4_ 1024

using frag  = __attribute__((ext_vector_type(8))) short;   // 8 bf16 = 4 VGPR
using f32x4 = __attribute__((ext_vector_type(4))) float;

__device__ __forceinline__ unsigned short bf16u(float f) {
    __hip_bfloat16 b = __float2bfloat16(f);
    return __builtin_bit_cast(unsigned short, b);
}

// ================= Phase 1a: Gxp[t] = x[t] @ Wi[t] + bi[t] + bh[t] (fp32) ======
// Output in MFMA C/D fragment layout:
// Gxp[(((t*8+rb)*64)+nb)*256 + lane*4 + rg]; rb=gr>>4, rloc=gr&15,
// lane=(gc&15)|((rloc>>2)<<4), rg=rloc&3, nb=gc>>4.
__global__ __launch_bounds__(256)
void lstm_phase1(const float* __restrict__ x, const float* __restrict__ Wi,
                 const float* __restrict__ bi, const float* __restrict__ bh,
                 float* __restrict__ Gxp)
{
    __shared__ float xs[32][36];
    __shared__ float ws1[32][128];

    const int tid = threadIdx.x;
    const int bid = blockIdx.x;
    const int t  = bid >> 5;
    const int rt = (bid >> 3) & 3;
    const int cn = bid & 7;
    const int r0 = rt * 32;
    const int c0 = cn * 128;

    const int tr  = tid >> 5;
    const int tc4 = tid & 31;
    const int xrow = tid >> 3;
    const int xk0  = (tid & 7) * 4;

    float acc[4][4] = {};

    for (int kc = 0; kc < I_; kc += 32) {
        __syncthreads();
        *(float4*)&xs[xrow][xk0] =
            *(const float4*)&x[(t * B_ + r0 + xrow) * I_ + kc + xk0];
        #pragma unroll
        for (int q = 0; q < 4; ++q) {
            int s  = q * 256 + tid;
            int k  = s >> 5;
            int c4 = (s & 31) * 4;
            *(float4*)&ws1[k][c4] =
                *(const float4*)&Wi[(t * I_ + kc + k) * G4_ + c0 + c4];
        }
        __syncthreads();
        #pragma unroll
        for (int k = 0; k < 32; ++k) {
            float a0 = xs[tr * 4 + 0][k];
            float a1 = xs[tr * 4 + 1][k];
            float a2 = xs[tr * 4 + 2][k];
            float a3 = xs[tr * 4 + 3][k];
            float4 w4 = *(const float4*)&ws1[k][tc4 * 4];
            acc[0][0] += a0 * w4.x; acc[0][1] += a0 * w4.y; acc[0][2] += a0 * w4.z; acc[0][3] += a0 * w4.w;
            acc[1][0] += a1 * w4.x; acc[1][1] += a1 * w4.y; acc[1][2] += a1 * w4.z; acc[1][3] += a1 * w4.w;
            acc[2][0] += a2 * w4.x; acc[2][1] += a2 * w4.y; acc[2][2] += a2 * w4.z; acc[2][3] += a2 * w4.w;
            acc[3][0] += a3 * w4.x; acc[3][1] += a3 * w4.y; acc[3][2] += a3 * w4.z; acc[3][3] += a3 * w4.w;
        }
    }

    const int col = c0 + tc4 * 4;
    float4 b1 = *(const float4*)&bi[t * G4_ + col];
    float4 b2 = *(const float4*)&bh[t * G4_ + col];
    float bs[4] = {b1.x + b2.x, b1.y + b2.y, b1.z + b2.z, b1.w + b2.w};
    #pragma unroll
    for (int i = 0; i < 4; ++i) {
        const int gr   = r0 + tr * 4 + i;
        const int rb   = gr >> 4;
        const int rloc = gr & 15;
        #pragma unroll
        for (int j = 0; j < 4; ++j) {
            const int gc   = col + j;
            const int lane = (gc & 15) | ((rloc >> 2) << 4);
            Gxp[(((size_t)t * 8 + rb) * 64 + (gc >> 4)) * 256 + lane * 4 + (rloc & 3)]
                = acc[i][j] + bs[j];
        }
    }
}

// ================= Phase 1b: repack Wh fp32 -> bf16 MFMA-B-fragment layout =====
__global__ __launch_bounds__(256)
void repack_wh(const float* __restrict__ Wh, unsigned short* __restrict__ Whp)
{
    int gid  = blockIdx.x * 256 + threadIdx.x;   // 4,194,304 tasks
    int lane = gid & 63;
    int nb   = (gid >> 6) & 63;
    int kb   = (gid >> 12) & 7;
    int t    = gid >> 15;
    int k0   = kb * 32 + (lane >> 4) * 8;
    int col  = nb * 16 + (lane & 15);
    const float* src = Wh + (size_t)(t * I_ + k0) * G4_ + col;
    unsigned short v[8];
    #pragma unroll
    for (int j = 0; j < 8; ++j) v[j] = bf16u(src[(size_t)j * G4_]);
    uint4 o;
    o.x = v[0] | ((unsigned)v[1] << 16);
    o.y = v[2] | ((unsigned)v[3] << 16);
    o.z = v[4] | ((unsigned)v[5] << 16);
    o.w = v[6] | ((unsigned)v[7] << 16);
    *(uint4*)(Whp + (size_t)gid * 8) = o;
}

// ================= Phase 2: column-split recurrence (32 blocks) ================
// Block (rg = bid&7, sl = bid>>3): batch rows rg*16..+16, h-cols sl*64..+64.
// The 4 slices of a row-group share bid%8 -> same XCD (L2-local exchange).
// h_t exchanged via tagged words: (t+1)<<16 | bf16(h) — word-atomic, no fences,
// replay-safe (stale tags carry identical deterministic values).
// 8 waves = 4 col-fragments (cb) x 2 K-halves (kh); K-halves reduce via LDS.
// K-hi waves poll foreign h while K-lo waves reduce+epilogue+publish.
__global__ __launch_bounds__(512, 1)
void lstm_rec(const float* __restrict__ h0, const float* __restrict__ c0in,
              const unsigned short* __restrict__ Whp,
              const float* __restrict__ Gxp, float* __restrict__ out,
              unsigned int* __restrict__ pub)
{
    __shared__ unsigned short h2[2][16][272];   // double-buffered bf16 h rows
    __shared__ float red[4][4][256];            // [cb][g][lane*4] K-hi partials

    const int tid  = threadIdx.x;
    const int wv   = tid >> 6;
    const int lane = tid & 63;
    const int rg   = blockIdx.x & 7;
    const int sl   = blockIdx.x >> 3;
    const int r0   = rg * 16;
    const int oc0  = sl * 64;
    const int kh   = wv >> 2;          // K-half: 0 -> kb 0..3, 1 -> kb 4..7
    const int cb   = wv & 3;           // 16-col fragment within own 64 cols
    const int lrow = lane & 15;
    const int lhi  = lane >> 4;

    {   // stage h0 -> h2[0] (full 256 cols)
        int row = tid >> 5;
        int cc  = (tid & 31) * 8;
        #pragma unroll
        for (int j = 0; j < 8; ++j)
            h2[0][row][cc + j] = bf16u(h0[(size_t)(r0 + row) * H_ + cc + j]);
    }

    float cst[4] = {0.f, 0.f, 0.f, 0.f};
    if (kh == 0) {
        #pragma unroll
        for (int rgi = 0; rgi < 4; ++rgi)
            cst[rgi] = c0in[(size_t)(r0 + lhi * 4 + rgi) * H_ + oc0 + cb * 16 + lrow];
    }

    // poll targets (K-hi threads): 12 foreign words each (16 rows x 192 cols)
    int prow[12], pcol[12];
    if (kh == 1) {
        const int ltid = tid - 256;
        #pragma unroll
        for (int k = 0; k < 12; ++k) {
            int w  = ltid + k * 256;
            int rr = w / 192;
            int fc = w - rr * 192;
            prow[k] = rr;
            pcol[k] = fc + (fc >= oc0 ? 64 : 0);
        }
    }

    const unsigned short* wl = Whp + (size_t)lane * 8;
    const float*          gl = Gxp + (size_t)lane * 4;

    // 4-deep weight fragment ring: br[kbl][g], kb = kh*4 + kbl
    frag br[4][4];
    #pragma unroll
    for (int kbl = 0; kbl < 4; ++kbl)
        #pragma unroll
        for (int g = 0; g < 4; ++g)
            br[kbl][g] = *(const frag*)(wl +
                (size_t)((kh * 4 + kbl) * 64 + g * 16 + sl * 4 + cb) * 512);

    f32x4 gxr[4];
    if (kh == 0) {
        #pragma unroll
        for (int g = 0; g < 4; ++g)
            gxr[g] = *(const f32x4*)(gl +
                (size_t)((size_t)rg * 64 + g * 16 + sl * 4 + cb) * 256);
    }

    __syncthreads();

    for (int t = 0; t < T_; ++t) {
        f32x4 acc[4];
        if (kh == 0) {
            #pragma unroll
            for (int g = 0; g < 4; ++g) acc[g] = gxr[g];
            if (t + 1 < T_) {
                #pragma unroll
                for (int g = 0; g < 4; ++g)
                    gxr[g] = *(const f32x4*)(gl +
                        (size_t)(((t + 1) * 8 + rg) * 64 + g * 16 + sl * 4 + cb) * 256);
            }
        } else {
            #pragma unroll
            for (int g = 0; g < 4; ++g) acc[g] = (f32x4){0.f, 0.f, 0.f, 0.f};
        }

        #pragma unroll
        for (int kbl = 0; kbl < 4; ++kbl) {
            const int kb = kh * 4 + kbl;
            frag a = *(const frag*)&h2[t & 1][lrow][kb * 32 + lhi * 8];
            #pragma unroll
            for (int g = 0; g < 4; ++g)
                acc[g] = __builtin_amdgcn_mfma_f32_16x16x32_bf16(
                    a, br[kbl][g], acc[g], 0, 0, 0);
            if (t + 1 < T_) {   // refill slot for next step (in flight ~a full step)
                #pragma unroll
                for (int g = 0; g < 4; ++g)
                    br[kbl][g] = *(const frag*)(wl +
                        (size_t)(((t + 1) * 8 + kb) * 64 + g * 16 + sl * 4 + cb) * 512);
            }
        }

        if (kh == 1) {   // stash K-hi partials
            #pragma unroll
            for (int g = 0; g < 4; ++g)
                *(f32x4*)&red[cb][g][lane * 4] = acc[g];
        }

        // barrier A (lgkm only — global prefetches stay in flight)
        __builtin_amdgcn_sched_barrier(0);
        asm volatile("s_waitcnt lgkmcnt(0)" ::: "memory");
        __builtin_amdgcn_s_barrier();
        __builtin_amdgcn_sched_barrier(0);

        if (kh == 0) {
            // reduce + epilogue + publish (own 64-col slice)
            #pragma unroll
            for (int g = 0; g < 4; ++g)
                acc[g] += *(const f32x4*)&red[cb][g][lane * 4];
            const int colb = oc0 + cb * 16 + lrow;
            #pragma unroll
            for (int rgi = 0; rgi < 4; ++rgi) {
                const int row = lhi * 4 + rgi;
                float gi = acc[0][rgi], gf = acc[1][rgi];
                float go = acc[2][rgi], gg = acc[3][rgi];
                float i_ = __builtin_amdgcn_rcpf(1.f + __expf(-gi));
                float f_ = __builtin_amdgcn_rcpf(1.f + __expf(-gf));
                float o_ = __builtin_amdgcn_rcpf(1.f + __expf(-go));
                float gt = 1.f - 2.f * __builtin_amdgcn_rcpf(__expf(2.f * gg) + 1.f);
                float c  = f_ * cst[rgi] + i_ * gt;
                cst[rgi] = c;
                float tc = 1.f - 2.f * __builtin_amdgcn_rcpf(__expf(2.f * c) + 1.f);
                float h  = o_ * tc;
                out[(size_t)(t * B_ + r0 + row) * H_ + colb] = h;
                unsigned short hb = bf16u(h);
                h2[(t + 1) & 1][row][colb] = hb;
                if (t + 1 < T_)
                    __hip_atomic_store(&pub[(size_t)(r0 + row) * H_ + colb],
                                       ((unsigned)(t + 1) << 16) | hb,
                                       __ATOMIC_RELAXED, __HIP_MEMORY_SCOPE_AGENT);
                if (t == T_ - 1) {
                    out[(size_t)T_ * B_ * H_ + (size_t)(r0 + row) * H_ + colb] = h;
                    out[(size_t)T_ * B_ * H_ + B_ * H_ + (size_t)(r0 + row) * H_ + colb] = c;
                }
            }
        } else if (t + 1 < T_) {
            // poll foreign slices of h_{t+1} -> h2[(t+1)&1]
            const unsigned want = (unsigned)(t + 1);
            unsigned pend = 0xFFFu;
            while (pend) {
                #pragma unroll
                for (int k = 0; k < 12; ++k) {
                    if (pend & (1u << k)) {
                        unsigned v = __hip_atomic_load(
                            &pub[(size_t)(r0 + prow[k]) * H_ + pcol[k]],
                            __ATOMIC_RELAXED, __HIP_MEMORY_SCOPE_AGENT);
                        if ((v >> 16) == want) {
                            h2[(t + 1) & 1][prow[k]][pcol[k]] =
                                (unsigned short)(v & 0xFFFFu);
                            pend &= ~(1u << k);
                        }
                    }
                }
            }
        }

        // barrier B (lgkm only)
        __builtin_amdgcn_sched_barrier(0);
        asm volatile("s_waitcnt lgkmcnt(0)" ::: "memory");
        __builtin_amdgcn_s_barrier();
        __builtin_amdgcn_sched_barrier(0);
    }
}

extern "C" void kernel_launch(void* const* d_in, const int* in_sizes, int n_in,
                              void* d_out, int out_size, void* d_ws, size_t ws_size,
                              hipStream_t stream) {
    const float* x  = (const float*)d_in[0];
    const float* h0 = (const float*)d_in[1];
    const float* c0 = (const float*)d_in[2];
    const float* Wi = (const float*)d_in[3];
    const float* bi = (const float*)d_in[4];
    const float* Wh = (const float*)d_in[5];
    const float* bh = (const float*)d_in[6];
    float* out = (float*)d_out;

    float*          Gxp = (float*)d_ws;                               // 64 MiB
    unsigned short* Whp = (unsigned short*)((char*)d_ws + 67108864);  // 64 MiB
    unsigned int*   pub = (unsigned int*)((char*)d_ws + 134217728);   // 128 KiB

    lstm_phase1<<<dim3(4096), dim3(256), 0, stream>>>(x, Wi, bi, bh, Gxp);
    repack_wh<<<dim3(16384), dim3(256), 0, stream>>>(Wh, Whp);
    lstm_rec<<<dim3(32), dim3(512), 0, stream>>>(h0, c0, Whp, Gxp, out, pub);
}